// Round 4
// baseline (238.834 us; speedup 1.0000x reference)
//
#include <hip/hip_runtime.h>

// TTTConv: depthwise causal conv1d, B=4, N=4096, D=2048, K=4, fp32.
// out[b,n,d] = bias[d] + sum_{k=0..3} w[d,k] * x[b, n-3+k, d]  (x[t<0]=0)
// states[b,d,k] = x[b, N-4+k, d]   (fused into last-strip blocks)
//
// Round-4 structure: strip-streaming. Previous rounds showed perf is
// insensitive to VGPR cap (56 vs 256: both ~70 us) -> burst-load lifecycle
// is the suspect, not per-wave MLP. Each block now streams a contiguous
// 32-row strip with a rolling 16-slot circular register window (fully
// unrolled, static indices), prefetch depth 8 rows: the load queue never
// drains, each row is read exactly once per block (halo amp 35/32 vs 11/8),
// and the block's read/write streams walk memory sequentially like a copy.

constexpr int B = 4, N = 4096, D = 2048, K = 4;
constexpr int BLK = 256;            // threads per block (4 waves)
constexpr int STRIP = 32;           // rows per block
constexpr int PF = 8;               // prefetch depth (rows in flight)
constexpr int CB = 16;              // circular-buffer slots (power of 2)
constexpr int DBLKS = 2;            // two 4KB half-rows cover D=2048 floats
constexpr int NSTRIPS = N / STRIP;  // 128
constexpr int NWG = B * NSTRIPS * DBLKS;  // 1024 workgroups

__global__ __launch_bounds__(BLK, 4) void tttconv_main(
    const float* __restrict__ x, const float* __restrict__ w,
    const float* __restrict__ bias, float* __restrict__ out,
    float* __restrict__ st)
{
    int bid = blockIdx.x;
    int b = bid / (NSTRIPS * DBLKS);
    int rem = bid % (NSTRIPS * DBLKS);
    int strip = rem / DBLKS;
    int dblk = rem % DBLKS;
    int dv = dblk * BLK + threadIdx.x;   // 0..511
    int d = dv * 4;
    int n0 = strip * STRIP;              // multiple of 32 -> (n0+i)&15 == i&15

    // w is (D,K) row-major: w[d+c][k] -> 16 contiguous floats at d*K
    const float4* w4 = (const float4*)(w + (size_t)d * K);
    float4 wr0 = w4[0];  // w[d+0][0..3]
    float4 wr1 = w4[1];
    float4 wr2 = w4[2];
    float4 wr3 = w4[3];
    float4 bv = *(const float4*)(bias + d);

    const float* xb = x + ((size_t)b * N) * D + d;
    float*       ob = out + ((size_t)b * N) * D + d;

    // Circular window: slot r&15 holds row r. Halo rows n0-3..n0-1 -> 13,14,15.
    float4 cb[CB];
    if (n0 == 0) {
        cb[13] = cb[14] = cb[15] = make_float4(0.f, 0.f, 0.f, 0.f);
    } else {
        cb[13] = *(const float4*)(xb + (size_t)(n0 - 3) * D);
        cb[14] = *(const float4*)(xb + (size_t)(n0 - 2) * D);
        cb[15] = *(const float4*)(xb + (size_t)(n0 - 1) * D);
    }
    // Prime the pipeline: rows n0..n0+PF-1 -> slots 0..7 (8 loads in flight).
    #pragma unroll
    for (int j = 0; j < PF; ++j)
        cb[j] = *(const float4*)(xb + (size_t)(n0 + j) * D);

    // Row i taps rows i-3..i  ->  slots (i+13)&15, (i+14)&15, (i+15)&15, i&15.
    #define COMPUTE_ROW(i)                                                      \
    {                                                                           \
        const float4 x0 = cb[((i) + 13) & 15];                                  \
        const float4 x1 = cb[((i) + 14) & 15];                                  \
        const float4 x2 = cb[((i) + 15) & 15];                                  \
        const float4 x3 = cb[(i) & 15];                                         \
        float4 a = bv;                                                          \
        a.x += wr0.x * x0.x + wr0.y * x1.x + wr0.z * x2.x + wr0.w * x3.x;       \
        a.y += wr1.x * x0.y + wr1.y * x1.y + wr1.z * x2.y + wr1.w * x3.y;       \
        a.z += wr2.x * x0.z + wr2.y * x1.z + wr2.z * x2.z + wr2.w * x3.z;       \
        a.w += wr3.x * x0.w + wr3.y * x1.w + wr3.z * x2.w + wr3.w * x3.w;       \
        *(float4*)(ob + (size_t)(n0 + (i)) * D) = a;                            \
    }

    // Main: compute row i, keep row i+PF's load in flight. Slot (i+8)&15 held
    // row i-8, dead since step i-5 -> scheduler has 5 rows of hoist slack.
    #pragma unroll
    for (int i = 0; i < STRIP - PF; ++i) {
        COMPUTE_ROW(i);
        cb[(i + PF) & 15] = *(const float4*)(xb + (size_t)(n0 + i + PF) * D);
    }
    // Drain: last PF rows, no more loads (nothing read past the strip end).
    #pragma unroll
    for (int i = STRIP - PF; i < STRIP; ++i) {
        COMPUTE_ROW(i);
    }
    #undef COMPUTE_ROW

    // Fused states: last strip's window ends holding rows N-4..N-1 in
    // slots (N-4)&15..(N-1)&15 = 12..15.  st is (B, D, K) row-major.
    if (strip == NSTRIPS - 1) {
        float* sbase = st + ((size_t)b * D + d) * K;
        float4 s0 = make_float4(cb[12].x, cb[13].x, cb[14].x, cb[15].x);
        float4 s1 = make_float4(cb[12].y, cb[13].y, cb[14].y, cb[15].y);
        float4 s2 = make_float4(cb[12].z, cb[13].z, cb[14].z, cb[15].z);
        float4 s3 = make_float4(cb[12].w, cb[13].w, cb[14].w, cb[15].w);
        *(float4*)(sbase + 0 * K) = s0;
        *(float4*)(sbase + 1 * K) = s1;
        *(float4*)(sbase + 2 * K) = s2;
        *(float4*)(sbase + 3 * K) = s3;
    }
}

extern "C" void kernel_launch(void* const* d_in, const int* in_sizes, int n_in,
                              void* d_out, int out_size, void* d_ws, size_t ws_size,
                              hipStream_t stream)
{
    const float* x    = (const float*)d_in[0];
    const float* w    = (const float*)d_in[1];
    const float* bias = (const float*)d_in[2];
    float* out = (float*)d_out;
    float* st  = out + (size_t)B * N * D;

    tttconv_main<<<NWG, BLK, 0, stream>>>(x, w, bias, out, st);
}

// Round 5
// 234.894 us; speedup vs baseline: 1.0168x; 1.0168x over previous
//
#include <hip/hip_runtime.h>

// TTTConv: depthwise causal conv1d, B=4, N=4096, D=2048, K=4, fp32.
// out[b,n,d] = bias[d] + sum_{k=0..3} w[d,k] * x[b, n-3+k, d]  (x[t<0]=0)
// states[b,d,k] = x[b, N-4+k, d]   (fused into last-chunk blocks)
// Floor: 128 MiB in + 128 MiB out -> ~42.6 us at 6.3 TB/s. Main kernel ~70.
//
// Round-5: PIN the load burst. Round-4 counters (VGPR_Count=36 despite a
// 16-slot register window and a 128-reg allowance) proved the compiler
// dissolves any source-level prefetch structure: it sinks loads to uses,
// leaving ~2-4 outstanding loads/wave. All prior rounds therefore ran the
// compiler's shallow schedule — the MLP theory was never tested. Fix:
// __builtin_amdgcn_sched_barrier(0) after the 11-load window loop forces
// all loads to issue before any compute (progressive vmcnt waits then let
// row-t compute overlap tail loads). Validity gate: VGPR_Count >= 80.

constexpr int B = 4, N = 4096, D = 2048, K = 4;
constexpr int T = 8;              // timesteps per thread
constexpr int BLK = 256;          // threads per block
constexpr int DV = D / 4;         // 512 float4 lanes across channels
constexpr int DBLKS = DV / BLK;   // 2 d-blocks per row
constexpr int NCHUNKS = N / T;    // 512 n-chunks
constexpr int NWG = B * NCHUNKS * DBLKS;  // 4096 workgroups

__global__ __launch_bounds__(BLK, 2) void tttconv_main(
    const float* __restrict__ x, const float* __restrict__ w,
    const float* __restrict__ bias, float* __restrict__ out,
    float* __restrict__ st)
{
    int bid = blockIdx.x;
    int b = bid / (NCHUNKS * DBLKS);
    int rem = bid % (NCHUNKS * DBLKS);
    int nchunk = rem / DBLKS;
    int dblk = rem % DBLKS;
    int dv = dblk * BLK + threadIdx.x;   // 0..511
    int d = dv * 4;
    int n0 = nchunk * T;

    const float* xbase = x + ((size_t)b * N) * D + d;
    float4 xin[T + K - 1];
    if (n0 >= K - 1) {
        // fast path: 11 independent loads — issued as one burst (see barrier)
        #pragma unroll
        for (int j = 0; j < T + K - 1; ++j)
            xin[j] = *(const float4*)(xbase + (size_t)(n0 - (K - 1) + j) * D);
    } else {
        #pragma unroll
        for (int j = 0; j < T + K - 1; ++j) {
            int n = n0 - (K - 1) + j;
            xin[j] = (n >= 0) ? *(const float4*)(xbase + (size_t)n * D)
                              : make_float4(0.f, 0.f, 0.f, 0.f);
        }
    }

    // Nothing crosses: all 11 global_load_dwordx4 are emitted above this
    // line, weight/bias loads and all compute stay below. The compiler's
    // progressive s_waitcnt vmcnt(N) still lets compute start at vmcnt(7).
    __builtin_amdgcn_sched_barrier(0);

    // w is (D,K) row-major: w[d+c][k] -> 16 contiguous floats at d*K
    const float4* w4 = (const float4*)(w + (size_t)d * K);
    float4 wr0 = w4[0];  // w[d+0][0..3]
    float4 wr1 = w4[1];
    float4 wr2 = w4[2];
    float4 wr3 = w4[3];
    float4 bv = *(const float4*)(bias + d);

    float* obase = out + ((size_t)b * N) * D + d;
    #pragma unroll
    for (int t = 0; t < T; ++t) {
        float4 acc = bv;
        // channel c uses wr_c; input index n0+t-3+k -> xin[t+k]
        acc.x += wr0.x * xin[t + 0].x + wr0.y * xin[t + 1].x + wr0.z * xin[t + 2].x + wr0.w * xin[t + 3].x;
        acc.y += wr1.x * xin[t + 0].y + wr1.y * xin[t + 1].y + wr1.z * xin[t + 2].y + wr1.w * xin[t + 3].y;
        acc.z += wr2.x * xin[t + 0].z + wr2.y * xin[t + 1].z + wr2.z * xin[t + 2].z + wr2.w * xin[t + 3].z;
        acc.w += wr3.x * xin[t + 0].w + wr3.y * xin[t + 1].w + wr3.z * xin[t + 2].w + wr3.w * xin[t + 3].w;
        *(float4*)(obase + (size_t)(n0 + t) * D) = acc;
    }

    // Fused states write: the last n-chunk already holds x[b, N-4+k, d] in regs.
    // xin[j] <-> n = n0 - 3 + j; n = N-4+k  ->  j = T-1+k  (k = 0..3).
    if (nchunk == NCHUNKS - 1) {
        float* sbase = st + ((size_t)b * D + d) * K;  // st is (B, D, K) row-major
        float4 s0 = make_float4(xin[T - 1].x, xin[T].x, xin[T + 1].x, xin[T + 2].x);
        float4 s1 = make_float4(xin[T - 1].y, xin[T].y, xin[T + 1].y, xin[T + 2].y);
        float4 s2 = make_float4(xin[T - 1].z, xin[T].z, xin[T + 1].z, xin[T + 2].z);
        float4 s3 = make_float4(xin[T - 1].w, xin[T].w, xin[T + 1].w, xin[T + 2].w);
        *(float4*)(sbase + 0 * K) = s0;
        *(float4*)(sbase + 1 * K) = s1;
        *(float4*)(sbase + 2 * K) = s2;
        *(float4*)(sbase + 3 * K) = s3;
    }
}

extern "C" void kernel_launch(void* const* d_in, const int* in_sizes, int n_in,
                              void* d_out, int out_size, void* d_ws, size_t ws_size,
                              hipStream_t stream)
{
    const float* x    = (const float*)d_in[0];
    const float* w    = (const float*)d_in[1];
    const float* bias = (const float*)d_in[2];
    float* out = (float*)d_out;
    float* st  = out + (size_t)B * N * D;

    tttconv_main<<<NWG, BLK, 0, stream>>>(x, w, bias, out, st);
}

// Round 7
// 231.990 us; speedup vs baseline: 1.0295x; 1.0125x over previous
//
#include <hip/hip_runtime.h>

// TTTConv: depthwise causal conv1d, B=4, N=4096, D=2048, K=4, fp32.
// out[b,n,d] = bias[d] + sum_{k=0..3} w[d,k] * x[b, n-3+k, d]  (x[t<0]=0)
// states[b,d,k] = x[b, N-4+k, d]   (fused into last-chunk blocks)
// Floor: 128 MiB in + 128 MiB out -> ~42.6 us at 6.3 TB/s. Main kernel ~70.
//
// Round-7 (= round-6 resubmitted; round-6 bench died on container
// acquisition, not kernel): isolate the store path. Ledger so far:
// schedule depth 1..11 outstanding loads/wave moves timing only 70<->82 us
// (rounds 0/1/3/4/5) -> neither MLP nor stream length is the lever.
// Untested residual mechanism: the harness fill re-poisons `out` right
// before us, leaving output lines dirty in OTHER XCDs' L2s; per-XCD L2s
// are non-coherent, so each normal store must acquire/invalidate through
// the fabric. Fix under test: __builtin_nontemporal_store (no-allocate
// streaming store) for the output stream ONLY — single-variable A/B vs
// round-3 (232.2 us).

constexpr int B = 4, N = 4096, D = 2048, K = 4;
constexpr int T = 8;              // timesteps per thread
constexpr int BLK = 256;          // threads per block
constexpr int DV = D / 4;         // 512 float4 lanes across channels
constexpr int DBLKS = DV / BLK;   // 2 d-blocks per row
constexpr int NCHUNKS = N / T;    // 512 n-chunks
constexpr int NWG = B * NCHUNKS * DBLKS;  // 4096 workgroups

typedef float v4f __attribute__((ext_vector_type(4)));

__device__ inline void nt_store4(float* p, float4 v) {
    v4f t = {v.x, v.y, v.z, v.w};
    __builtin_nontemporal_store(t, (v4f*)p);
}

__global__ __launch_bounds__(BLK, 2) void tttconv_main(
    const float* __restrict__ x, const float* __restrict__ w,
    const float* __restrict__ bias, float* __restrict__ out,
    float* __restrict__ st)
{
    int bid = blockIdx.x;
    int b = bid / (NCHUNKS * DBLKS);
    int rem = bid % (NCHUNKS * DBLKS);
    int nchunk = rem / DBLKS;
    int dblk = rem % DBLKS;
    int dv = dblk * BLK + threadIdx.x;   // 0..511
    int d = dv * 4;
    int n0 = nchunk * T;

    // w is (D,K) row-major: w[d+c][k] -> 16 contiguous floats at d*K
    const float4* w4 = (const float4*)(w + (size_t)d * K);
    float4 wr0 = w4[0];  // w[d+0][0..3]
    float4 wr1 = w4[1];
    float4 wr2 = w4[2];
    float4 wr3 = w4[3];
    float4 bv = *(const float4*)(bias + d);

    const float* xbase = x + ((size_t)b * N) * D + d;
    float4 xin[T + K - 1];
    if (n0 >= K - 1) {
        // fast path: 11 independent loads
        #pragma unroll
        for (int j = 0; j < T + K - 1; ++j)
            xin[j] = *(const float4*)(xbase + (size_t)(n0 - (K - 1) + j) * D);
    } else {
        #pragma unroll
        for (int j = 0; j < T + K - 1; ++j) {
            int n = n0 - (K - 1) + j;
            xin[j] = (n >= 0) ? *(const float4*)(xbase + (size_t)n * D)
                              : make_float4(0.f, 0.f, 0.f, 0.f);
        }
    }

    float* obase = out + ((size_t)b * N) * D + d;
    #pragma unroll
    for (int t = 0; t < T; ++t) {
        float4 acc = bv;
        // channel c uses wr_c; input index n0+t-3+k -> xin[t+k]
        acc.x += wr0.x * xin[t + 0].x + wr0.y * xin[t + 1].x + wr0.z * xin[t + 2].x + wr0.w * xin[t + 3].x;
        acc.y += wr1.x * xin[t + 0].y + wr1.y * xin[t + 1].y + wr1.z * xin[t + 2].y + wr1.w * xin[t + 3].y;
        acc.z += wr2.x * xin[t + 0].z + wr2.y * xin[t + 1].z + wr2.z * xin[t + 2].z + wr2.w * xin[t + 3].z;
        acc.w += wr3.x * xin[t + 0].w + wr3.y * xin[t + 1].w + wr3.z * xin[t + 2].w + wr3.w * xin[t + 3].w;
        nt_store4(obase + (size_t)(n0 + t) * D, acc);   // streaming store: no L2 ownership acquire
    }

    // Fused states write: the last n-chunk already holds x[b, N-4+k, d] in regs.
    // xin[j] <-> n = n0 - 3 + j; n = N-4+k  ->  j = T-1+k  (k = 0..3).
    if (nchunk == NCHUNKS - 1) {
        float* sbase = st + ((size_t)b * D + d) * K;  // st is (B, D, K) row-major
        float4 s0 = make_float4(xin[T - 1].x, xin[T].x, xin[T + 1].x, xin[T + 2].x);
        float4 s1 = make_float4(xin[T - 1].y, xin[T].y, xin[T + 1].y, xin[T + 2].y);
        float4 s2 = make_float4(xin[T - 1].z, xin[T].z, xin[T + 1].z, xin[T + 2].z);
        float4 s3 = make_float4(xin[T - 1].w, xin[T].w, xin[T + 1].w, xin[T + 2].w);
        *(float4*)(sbase + 0 * K) = s0;
        *(float4*)(sbase + 1 * K) = s1;
        *(float4*)(sbase + 2 * K) = s2;
        *(float4*)(sbase + 3 * K) = s3;
    }
}

extern "C" void kernel_launch(void* const* d_in, const int* in_sizes, int n_in,
                              void* d_out, int out_size, void* d_ws, size_t ws_size,
                              hipStream_t stream)
{
    const float* x    = (const float*)d_in[0];
    const float* w    = (const float*)d_in[1];
    const float* bias = (const float*)d_in[2];
    float* out = (float*)d_out;
    float* st  = out + (size_t)B * N * D;

    tttconv_main<<<NWG, BLK, 0, stream>>>(x, w, bias, out, st);
}